// Round 3
// baseline (482.660 us; speedup 1.0000x reference)
//
#include <hip/hip_runtime.h>
#include <stdint.h>

typedef __bf16 bf16;
typedef __bf16 bf16x4 __attribute__((ext_vector_type(4)));
typedef __bf16 bf16x8 __attribute__((ext_vector_type(8)));
typedef float  f32x4  __attribute__((ext_vector_type(4)));

constexpr int BB = 8;
constexpr int NN = 2048;
constexpr int EE = 768;
constexpr int MM = BB * NN;   // 16384
constexpr int E2 = 2 * EE;    // 1536 (Q|K merged)

typedef const __attribute__((address_space(1))) void* as1_cvp;
typedef __attribute__((address_space(3))) void* as3_vp;

static __device__ __forceinline__ void gld16(const void* g, void* l) {
  __builtin_amdgcn_global_load_lds((as1_cvp)g, (as3_vp)l, 16, 0, 0);
}

// ---------------- x -> bf16 hi/lo split ----------------
__global__ __launch_bounds__(256) void k_splitx(const float4* __restrict__ x,
                                                bf16x4* __restrict__ hi,
                                                bf16x4* __restrict__ lo, int n4) {
  int i = blockIdx.x * 256 + threadIdx.x;
  int st = gridDim.x * 256;
  for (; i < n4; i += st) {
    float4 v = x[i];
    bf16x4 h, l;
    h[0] = (bf16)v.x; l[0] = (bf16)(v.x - (float)h[0]);
    h[1] = (bf16)v.y; l[1] = (bf16)(v.y - (float)h[1]);
    h[2] = (bf16)v.z; l[2] = (bf16)(v.z - (float)h[2]);
    h[3] = (bf16)v.w; l[3] = (bf16)(v.w - (float)h[3]);
    hi[i] = h; lo[i] = l;
  }
}

// ---------------- weight prep ----------------
__global__ __launch_bounds__(256) void k_wprep(const float4* __restrict__ wq,
                                               const float4* __restrict__ wk,
                                               const float4* __restrict__ wv,
                                               const float4* __restrict__ wo,
                                               bf16x4* __restrict__ qkh, bf16x4* __restrict__ qkl,
                                               bf16x4* __restrict__ vb,  bf16x4* __restrict__ ob) {
  const int n4 = EE * EE / 4;
  int sel = blockIdx.y;
  int i = blockIdx.x * 256 + threadIdx.x;
  int st = gridDim.x * 256;
  for (; i < n4; i += st) {
    if (sel <= 1) {
      float4 v = sel == 0 ? wq[i] : wk[i];
      bf16x4 h, l;
      h[0] = (bf16)v.x; l[0] = (bf16)(v.x - (float)h[0]);
      h[1] = (bf16)v.y; l[1] = (bf16)(v.y - (float)h[1]);
      h[2] = (bf16)v.z; l[2] = (bf16)(v.z - (float)h[2]);
      h[3] = (bf16)v.w; l[3] = (bf16)(v.w - (float)h[3]);
      int o = i + sel * n4;
      qkh[o] = h; qkl[o] = l;
    } else {
      float4 v = sel == 2 ? wv[i] : wo[i];
      bf16x4 h;
      h[0] = (bf16)v.x; h[1] = (bf16)v.y; h[2] = (bf16)v.z; h[3] = (bf16)v.w;
      if (sel == 2) vb[i] = h; else ob[i] = h;
    }
  }
}

// ================= NEW: split-bf16 pipelined GEMM =================
// C[M,N] = (Ah+Al)[M,K] @ (Bh+Bl)[N,K]^T, 3-product compensation.
// 256x128 tile, BK=32, 8 waves (4Mx2N, 64x64 each), 3-buffer LDS ring,
// counted vmcnt(6) (one wait per K-tile, never drained in steady state).
// EPI: 0 = bf16 hi/lo pair (C0,C1); 1 = float*cscale (C0)
template <int EPI>
__global__ __launch_bounds__(512, 2) void k_gemm_split8(
    const bf16* __restrict__ Ah, const bf16* __restrict__ Al,
    const bf16* __restrict__ Bh, const bf16* __restrict__ Bl,
    void* __restrict__ C0, void* __restrict__ C1,
    int Kdim, int lda, int ldb, int ldc,
    long long sA, long long sB, long long sC, float cscale) {
  // per buffer: Ah[256][32] @0, Al @16384, Bh[128][32] @32768, Bl @40960 (48 KiB)
  __shared__ __align__(16) char sm[3 * 49152];

  const int tid = threadIdx.x;
  const int lane = tid & 63, wid = tid >> 6;
  const int lr = lane & 15, lq = lane >> 4;
  const int wm = wid >> 1, wn = wid & 1;

  // XCD-aware bijective swizzle on the (x,y) plane (nxy % 8 == 0 for all grids)
  const int nbx = gridDim.x;
  int lin = blockIdx.x + blockIdx.y * nbx;
  int chunk = (nbx * gridDim.y) >> 3;
  int sw = (lin & 7) * chunk + (lin >> 3);
  const int col0 = (sw % nbx) * 128;
  const int row0 = (sw / nbx) * 256;
  const long long bz = blockIdx.z;

  const bf16* pAh = Ah + bz * sA + (size_t)row0 * lda;
  const bf16* pAl = Al + bz * sA + (size_t)row0 * lda;
  const bf16* pBh = Bh + bz * sB + (size_t)col0 * ldb;
  const bf16* pBl = Bl + bz * sB + (size_t)col0 * ldb;

  // K-invariant ds_read byte offsets (swizzled) within a tensor tile
  int aoff[4], boff[4];
#pragma unroll
  for (int m = 0; m < 4; ++m) {
    int row = wm * 64 + m * 16 + lr;
    int o = row * 64 + lq * 16;
    aoff[m] = o ^ (((o >> 7) & 3) << 4);
  }
#pragma unroll
  for (int n = 0; n < 4; ++n) {
    int row = wn * 64 + n * 16 + lr;
    int o = row * 64 + lq * 16;
    boff[n] = o ^ (((o >> 7) & 3) << 4);
  }

  const int o0 = tid * 16;
  // stage one half (hi or lo) of K-tile tk into ring buffer buf: 3 x gld16
  auto stage_half = [&](int buf, int tk, bool hi) {
    char* base = sm + buf * 49152;
    const bf16* a = hi ? pAh : pAl;
    const bf16* b = hi ? pBh : pBl;
    char* da = base + (hi ? 0 : 16384);
    char* db = base + (hi ? 32768 : 40960);
#pragma unroll
    for (int r = 0; r < 2; ++r) {
      int o = o0 + r * 8192;
      int row = o >> 6;
      int cb = (o & 63) ^ (((o >> 7) & 3) << 4);  // inverse swizzle on source
      gld16((const char*)(a + (size_t)row * lda) + tk * 64 + cb, da + o);
    }
    {
      int row = o0 >> 6;  // 0..127
      int cb = (o0 & 63) ^ (((o0 >> 7) & 3) << 4);
      gld16((const char*)(b + (size_t)row * ldb) + tk * 64 + cb, db + o0);
    }
  };

  f32x4 acc[4][4] = {};
  const int NT = Kdim >> 5;  // K-tiles of 32

  // prologue: tiles 0,1 -> bufs 0,1 (12 loads); wait tile0 (keep tile1 in flight)
  stage_half(0, 0, true);  stage_half(0, 0, false);
  stage_half(1, 1, true);  stage_half(1, 1, false);
  asm volatile("s_waitcnt vmcnt(6)" ::: "memory");
  __builtin_amdgcn_s_barrier();

  bf16x8 bhf[4], blf[4];
  for (int j = 0; j < NT; ++j) {
    const char* bb = sm + (j % 3) * 49152;
    const int nb = (j + 2) % 3;
    const bool pf = (j + 2) < NT;
#pragma unroll
    for (int h = 0; h < 2; ++h) {
      if (pf) stage_half(nb, j + 2, h == 0);
      bf16x8 ah[2], al[2];
      if (h == 0) {
#pragma unroll
        for (int n = 0; n < 4; ++n) {
          bhf[n] = *(const bf16x8*)(bb + 32768 + boff[n]);
          blf[n] = *(const bf16x8*)(bb + 40960 + boff[n]);
        }
      }
#pragma unroll
      for (int mm = 0; mm < 2; ++mm) {
        ah[mm] = *(const bf16x8*)(bb + aoff[h * 2 + mm]);
        al[mm] = *(const bf16x8*)(bb + 16384 + aoff[h * 2 + mm]);
      }
      if (h == 1) {  // guarantee tile j+1 resident before next iter reads it
        if (j < NT - 2)       asm volatile("s_waitcnt vmcnt(6)" ::: "memory");
        else if (j == NT - 2) asm volatile("s_waitcnt vmcnt(0)" ::: "memory");
      }
      __builtin_amdgcn_s_barrier();
      asm volatile("s_waitcnt lgkmcnt(0)" ::: "memory");
      __builtin_amdgcn_sched_barrier(0);
      __builtin_amdgcn_s_setprio(1);
#pragma unroll
      for (int mm = 0; mm < 2; ++mm)
#pragma unroll
        for (int n = 0; n < 4; ++n) {
          acc[h * 2 + mm][n] = __builtin_amdgcn_mfma_f32_16x16x32_bf16(ah[mm], bhf[n], acc[h * 2 + mm][n], 0, 0, 0);
          acc[h * 2 + mm][n] = __builtin_amdgcn_mfma_f32_16x16x32_bf16(ah[mm], blf[n], acc[h * 2 + mm][n], 0, 0, 0);
          acc[h * 2 + mm][n] = __builtin_amdgcn_mfma_f32_16x16x32_bf16(al[mm], bhf[n], acc[h * 2 + mm][n], 0, 0, 0);
        }
      __builtin_amdgcn_s_setprio(0);
      __builtin_amdgcn_s_barrier();
    }
  }

  // epilogue: C row=(lane>>4)*4+reg, col=lane&15 (verified layout)
#pragma unroll
  for (int m = 0; m < 4; ++m) {
#pragma unroll
    for (int n = 0; n < 4; ++n) {
      f32x4 v = acc[m][n];
#pragma unroll
      for (int jj = 0; jj < 4; ++jj) {
        size_t r = (size_t)(row0 + wm * 64 + m * 16 + lq * 4 + jj);
        size_t c = (size_t)(col0 + wn * 64 + n * 16 + lr);
        size_t idx = r * (size_t)ldc + c;
        float val = v[jj] * cscale;
        if constexpr (EPI == 0) {
          bf16* Chp = (bf16*)C0 + bz * sC;
          bf16* Clp = (bf16*)C1 + bz * sC;
          bf16 hh = (bf16)val;
          Chp[idx] = hh;
          Clp[idx] = (bf16)(val - (float)hh);
        } else {
          float* Cp = (float*)C0 + bz * sC;
          Cp[idx] = val;
        }
      }
    }
  }
}

// ---------------- old 128^2 GEMM (non-split users: V-proj, PV, O-proj) ----------------
// EPI: 1 = float*cscale (C0); 2 = bf16 (C0); 3 = bf16 transposed V write
template <bool SPLIT, int EPI>
__global__ __launch_bounds__(256, 2) void k_gemm(
    const bf16* __restrict__ Ah, const bf16* __restrict__ Al,
    const bf16* __restrict__ Bh, const bf16* __restrict__ Bl,
    void* __restrict__ C0, void* __restrict__ C1,
    int Kdim, int lda, int ldb, int ldc,
    long long sA, long long sB, long long sC, float cscale) {
  constexpr int NTILES = SPLIT ? 4 : 2;
  __shared__ __align__(16) bf16 smm[NTILES * 128 * 64];
  bf16* smAh = smm;
  bf16* smBh = smm + 128 * 64;
  bf16* smAl = SPLIT ? smm + 2 * 128 * 64 : nullptr;
  bf16* smBl = SPLIT ? smm + 3 * 128 * 64 : nullptr;

  const int tid = threadIdx.x;
  const int lane = tid & 63, wid = tid >> 6;
  const int lr = lane & 15, lq = lane >> 4;
  const int wr = (wid >> 1) * 64, wc = (wid & 1) * 64;
  const long long bz = blockIdx.z;
  const int col0 = blockIdx.x * 128, row0 = blockIdx.y * 128;

  const bf16* pAh = Ah + bz * sA;
  const bf16* pBh = Bh + bz * sB;
  const bf16* pAl = SPLIT ? (Al + bz * sA) : nullptr;
  const bf16* pBl = SPLIT ? (Bl + bz * sB) : nullptr;

  f32x4 acc[4][4] = {};

  for (int kt = 0; kt < Kdim; kt += 64) {
    {
      int o = tid * 16;
#pragma unroll
      for (int r = 0; r < 4; r++, o += 4096) {
        int row = o >> 7;
        int c = (o & 127) ^ ((row & 7) << 4);
        gld16((const char*)(pAh + (size_t)(row0 + row) * lda + kt) + c, (char*)smAh + o);
        gld16((const char*)(pBh + (size_t)(col0 + row) * ldb + kt) + c, (char*)smBh + o);
        if constexpr (SPLIT) {
          gld16((const char*)(pAl + (size_t)(row0 + row) * lda + kt) + c, (char*)smAl + o);
          gld16((const char*)(pBl + (size_t)(col0 + row) * ldb + kt) + c, (char*)smBl + o);
        }
      }
    }
    __syncthreads();
#pragma unroll
    for (int kk = 0; kk < 2; kk++) {
      bf16x8 ah[4], bh[4], al[4], bl[4];
#pragma unroll
      for (int i = 0; i < 4; i++) {
        int ar = wr + i * 16 + lr;
        int ao = ar * 128 + ((kk * 64 + lq * 16) ^ ((ar & 7) << 4));
        ah[i] = *(const bf16x8*)((const char*)smAh + ao);
        int br = wc + i * 16 + lr;
        int bo = br * 128 + ((kk * 64 + lq * 16) ^ ((br & 7) << 4));
        bh[i] = *(const bf16x8*)((const char*)smBh + bo);
        if constexpr (SPLIT) {
          al[i] = *(const bf16x8*)((const char*)smAl + ao);
          bl[i] = *(const bf16x8*)((const char*)smBl + bo);
        }
      }
#pragma unroll
      for (int i = 0; i < 4; i++)
#pragma unroll
        for (int j = 0; j < 4; j++) {
          acc[i][j] = __builtin_amdgcn_mfma_f32_16x16x32_bf16(ah[i], bh[j], acc[i][j], 0, 0, 0);
          if constexpr (SPLIT) {
            acc[i][j] = __builtin_amdgcn_mfma_f32_16x16x32_bf16(ah[i], bl[j], acc[i][j], 0, 0, 0);
            acc[i][j] = __builtin_amdgcn_mfma_f32_16x16x32_bf16(al[i], bh[j], acc[i][j], 0, 0, 0);
          }
        }
    }
    __syncthreads();
  }

#pragma unroll
  for (int i = 0; i < 4; i++) {
#pragma unroll
    for (int j2 = 0; j2 < 4; j2++) {
      f32x4 v = acc[i][j2];
      if constexpr (EPI == 3) {
        int r0 = row0 + wr + i * 16 + lq * 4;
        int c = col0 + wc + j2 * 16 + lr;
        int b = r0 >> 11, n0 = r0 & 2047;
        bf16x4 t;
#pragma unroll
        for (int j = 0; j < 4; j++) t[j] = (bf16)(v[j] * cscale);
        *(bf16x4*)((bf16*)C0 + ((size_t)b * EE + c) * NN + n0) = t;
      } else {
#pragma unroll
        for (int j = 0; j < 4; j++) {
          size_t r = (size_t)(row0 + wr + i * 16 + lq * 4 + j);
          size_t c = (size_t)(col0 + wc + j2 * 16 + lr);
          size_t idx = r * (size_t)ldc + c;
          float val = v[j] * cscale;
          if constexpr (EPI == 1) {
            float* Cp = (float*)C0 + bz * sC;
            Cp[idx] = val;
          } else {
            bf16* Cp = (bf16*)C0 + bz * sC;
            Cp[idx] = (bf16)val;
          }
        }
      }
    }
  }
}

// ---------------- row softmax in-place: S row fp32 -> P bf16 in first half ----------------
__global__ __launch_bounds__(256) void k_softmax(float* __restrict__ S) {
  size_t row = blockIdx.x;
  float* srow = S + row * (size_t)NN;
  int tid = threadIdx.x;
  int wid = tid >> 6, lane = tid & 63;
  const float4* s4 = (const float4*)srow;
  float4 v0 = s4[tid * 2], v1 = s4[tid * 2 + 1];
  float vv[8] = {v0.x, v0.y, v0.z, v0.w, v1.x, v1.y, v1.z, v1.w};
  float m = vv[0];
#pragma unroll
  for (int j = 1; j < 8; j++) m = fmaxf(m, vv[j]);
#pragma unroll
  for (int d = 1; d < 64; d <<= 1) m = fmaxf(m, __shfl_xor(m, d));
  __shared__ float red[8];
  if (lane == 0) red[wid] = m;
  __syncthreads();
  m = fmaxf(fmaxf(red[0], red[1]), fmaxf(red[2], red[3]));
  float e[8];
  float ssum = 0.f;
#pragma unroll
  for (int j = 0; j < 8; j++) { e[j] = __expf(vv[j] - m); ssum += e[j]; }
#pragma unroll
  for (int d = 1; d < 64; d <<= 1) ssum += __shfl_xor(ssum, d);
  if (lane == 0) red[4 + wid] = ssum;
  __syncthreads();
  ssum = red[4] + red[5] + red[6] + red[7];
  float inv = 1.0f / ssum;
  bf16x8 p;
#pragma unroll
  for (int j = 0; j < 8; j++) p[j] = (bf16)(e[j] * inv);
  *(bf16x8*)((bf16*)srow + tid * 8) = p;
}

// ---------------- host ----------------
extern "C" void kernel_launch(void* const* d_in, const int* in_sizes, int n_in,
                              void* d_out, int out_size, void* d_ws, size_t ws_size,
                              hipStream_t stream) {
  const float* x  = (const float*)d_in[0];
  const float* Wq = (const float*)d_in[1];
  const float* Wk = (const float*)d_in[2];
  const float* Wv = (const float*)d_in[3];
  const float* Wo = (const float*)d_in[4];
  float* out = (float*)d_out;
  char* ws = (char*)d_ws;

  const size_t szXE = (size_t)MM * EE * 2;      // 25.17 MB
  const size_t szWb = (size_t)EE * EE * 2;      // 1.18 MB
  const size_t szQKh = (size_t)MM * E2 * 2;     // 50.33 MB
  const size_t szS1 = (size_t)NN * NN * 4;      // 16.78 MB

  bf16* xhi = (bf16*)(ws);
  bf16* xlo = (bf16*)(ws + szXE);
  char* wb  = ws + 2 * szXE;
  bf16* wqkh = (bf16*)(wb);
  bf16* wqkl = (bf16*)(wb + 2 * szWb);
  bf16* wvb  = (bf16*)(wb + 4 * szWb);
  bf16* wob  = (bf16*)(wb + 5 * szWb);
  char* qkb = wb + 6 * szWb;
  bf16* QKh = (bf16*)(qkb);
  bf16* QKl = (bf16*)(qkb + szQKh);
  bf16* Vt  = (bf16*)(qkb + 2 * szQKh);
  char* Sb  = qkb + 2 * szQKh + szXE;
  float* S  = (float*)Sb;
  bf16* Ao  = (bf16*)ws;  // overlay x (dead after projections)

  size_t oS = (size_t)(Sb - ws);
  size_t avail = ws_size > oS ? ws_size - oS : 0;
  int G = 8;
  while (G > 1 && (size_t)G * szS1 > avail) G >>= 1;

  k_splitx<<<2048, 256, 0, stream>>>((const float4*)x, (bf16x4*)xhi, (bf16x4*)xlo, MM * EE / 4);
  k_wprep<<<dim3(144, 4), 256, 0, stream>>>((const float4*)Wq, (const float4*)Wk,
                                            (const float4*)Wv, (const float4*)Wo,
                                            (bf16x4*)wqkh, (bf16x4*)wqkl, (bf16x4*)wvb, (bf16x4*)wob);

  // merged Q|K projection (split, pipelined): grid (1536/128, 16384/256)
  k_gemm_split8<0><<<dim3(E2 / 128, MM / 256, 1), 512, 0, stream>>>(
      xhi, xlo, wqkh, wqkl, QKh, QKl, EE, EE, EE, E2, 0, 0, 0, 1.0f);
  // V projection, written transposed
  k_gemm<false, 3><<<dim3(EE / 128, MM / 128, 1), 256, 0, stream>>>(
      xhi, nullptr, wvb, nullptr, Vt, nullptr, EE, EE, EE, 0, 0, 0, 0, 1.0f);

  const long long sQK = (long long)NN * E2;
  for (int g = 0; g < BB; g += G) {
    const bf16* Qh = QKh + (size_t)g * NN * E2;
    const bf16* Ql = QKl + (size_t)g * NN * E2;
    // S = 8 * Q @ K^T (split, pipelined): grid (2048/128, 2048/256, G)
    k_gemm_split8<1><<<dim3(NN / 128, NN / 256, G), 512, 0, stream>>>(
        Qh, Ql, Qh + EE, Ql + EE, S, nullptr, EE, E2, E2, NN,
        sQK, sQK, (long long)NN * NN, 8.0f);
    k_softmax<<<G * NN, 256, 0, stream>>>(S);
    k_gemm<false, 2><<<dim3(EE / 128, NN / 128, G), 256, 0, stream>>>(
        (const bf16*)S, nullptr, Vt + (size_t)g * EE * NN, nullptr,
        Ao + (size_t)g * NN * EE, nullptr, NN, 2 * NN, NN, EE,
        2LL * NN * NN, (long long)EE * NN, (long long)NN * EE, 1.0f);
  }

  k_gemm<false, 1><<<dim3(EE / 128, MM / 128, 1), 256, 0, stream>>>(
      Ao, nullptr, wob, nullptr, out, nullptr, EE, EE, EE, EE, 0, 0, 0, 1.0f);
}

// Round 4
// 481.007 us; speedup vs baseline: 1.0034x; 1.0034x over previous
//
#include <hip/hip_runtime.h>
#include <stdint.h>

typedef __bf16 bf16;
typedef __bf16 bf16x4 __attribute__((ext_vector_type(4)));
typedef __bf16 bf16x8 __attribute__((ext_vector_type(8)));
typedef float  f32x4  __attribute__((ext_vector_type(4)));

constexpr int BB = 8;
constexpr int NN = 2048;
constexpr int EE = 768;
constexpr int MM = BB * NN;   // 16384
constexpr int E2 = 2 * EE;    // 1536 (Q|K merged)

typedef const __attribute__((address_space(1))) void* as1_cvp;
typedef __attribute__((address_space(3))) void* as3_vp;

static __device__ __forceinline__ void gld16(const void* g, void* l) {
  __builtin_amdgcn_global_load_lds((as1_cvp)g, (as3_vp)l, 16, 0, 0);
}

// ---------------- x -> bf16 hi/lo split ----------------
__global__ __launch_bounds__(256) void k_splitx(const float4* __restrict__ x,
                                                bf16x4* __restrict__ hi,
                                                bf16x4* __restrict__ lo, int n4) {
  int i = blockIdx.x * 256 + threadIdx.x;
  int st = gridDim.x * 256;
  for (; i < n4; i += st) {
    float4 v = x[i];
    bf16x4 h, l;
    h[0] = (bf16)v.x; l[0] = (bf16)(v.x - (float)h[0]);
    h[1] = (bf16)v.y; l[1] = (bf16)(v.y - (float)h[1]);
    h[2] = (bf16)v.z; l[2] = (bf16)(v.z - (float)h[2]);
    h[3] = (bf16)v.w; l[3] = (bf16)(v.w - (float)h[3]);
    hi[i] = h; lo[i] = l;
  }
}

// ---------------- weight prep ----------------
__global__ __launch_bounds__(256) void k_wprep(const float4* __restrict__ wq,
                                               const float4* __restrict__ wk,
                                               const float4* __restrict__ wv,
                                               const float4* __restrict__ wo,
                                               bf16x4* __restrict__ qkh, bf16x4* __restrict__ qkl,
                                               bf16x4* __restrict__ vb,  bf16x4* __restrict__ ob) {
  const int n4 = EE * EE / 4;
  int sel = blockIdx.y;
  int i = blockIdx.x * 256 + threadIdx.x;
  int st = gridDim.x * 256;
  for (; i < n4; i += st) {
    if (sel <= 1) {
      float4 v = sel == 0 ? wq[i] : wk[i];
      bf16x4 h, l;
      h[0] = (bf16)v.x; l[0] = (bf16)(v.x - (float)h[0]);
      h[1] = (bf16)v.y; l[1] = (bf16)(v.y - (float)h[1]);
      h[2] = (bf16)v.z; l[2] = (bf16)(v.z - (float)h[2]);
      h[3] = (bf16)v.w; l[3] = (bf16)(v.w - (float)h[3]);
      int o = i + sel * n4;
      qkh[o] = h; qkl[o] = l;
    } else {
      float4 v = sel == 2 ? wv[i] : wo[i];
      bf16x4 h;
      h[0] = (bf16)v.x; h[1] = (bf16)v.y; h[2] = (bf16)v.z; h[3] = (bf16)v.w;
      if (sel == 2) vb[i] = h; else ob[i] = h;
    }
  }
}

// ================= 256x256 8-phase GEMM with virtual 3-panel K (K = 3*768) =================
// C[M,N] = sum_p A_p[M,768] @ B_p[N,768]^T  (panels via base-pointer select; plain bf16)
// BM=BN=256, BK=64, 8 waves (2M x 4N), per-wave 128x64, LDS 128 KiB double-buffered.
// Per tile: 4 phases x {stage 1 half-tile, ds_read subtile, lgkmcnt(0), 16 MFMA, barrier};
// counted s_waitcnt vmcnt(4) once per K-tile (never 0 until the end).
// EPI: 0 = bf16 hi/lo pair (C0,C1); 1 = float*cscale (C0)
template <int EPI>
__global__ __launch_bounds__(512, 2) void k_gemm3p8(
    const bf16* __restrict__ A0, const bf16* __restrict__ A1, const bf16* __restrict__ A2,
    const bf16* __restrict__ B0, const bf16* __restrict__ B1, const bf16* __restrict__ B2,
    void* __restrict__ C0, void* __restrict__ C1,
    int lda, int ldb, int ldc,
    long long sA, long long sB, long long sC, float cscale) {
  constexpr int NT = 36;  // 2304 / 64
  __shared__ __align__(16) char sm[131072];  // A[2][256][128B] @0, B[2][256][128B] @65536

  const int tid = threadIdx.x;
  const int lane = tid & 63, wid = tid >> 6;
  const int lr = lane & 15, lq = lane >> 4;
  const int wm = wid >> 2, wn = wid & 3;  // 2M x 4N

  // XCD-aware bijective swizzle on (x,y) plane (nblocks % 8 == 0 for all call sites)
  const int nbx = gridDim.x;
  int lin = blockIdx.x + blockIdx.y * nbx;
  int chunk = (nbx * gridDim.y) >> 3;
  int sw = (lin & 7) * chunk + (lin >> 3);
  const int col0 = (sw % nbx) * 256;
  const int row0 = (sw / nbx) * 256;
  const long long bz = blockIdx.z;

  const bf16* pA[3] = {A0 + bz * sA, A1 + bz * sA, A2 + bz * sA};
  const bf16* pB[3] = {B0 + bz * sB, B1 + bz * sB, B2 + bz * sB};

  // stage one half-tile (16 KB): tensor 0=A,1=B; half 0/1; K-tile tk; dest buffer buf
  auto stage = [&](int tensor, int half, int tk, int buf) {
    int pi = tk / 12;
    int ko = (tk - pi * 12) * 64;
    const bf16* base;
    if (tensor == 0) base = pi == 0 ? pA[0] : (pi == 1 ? pA[1] : pA[2]);
    else             base = pi == 0 ? pB[0] : (pi == 1 ? pB[1] : pB[2]);
    int ld = tensor == 0 ? lda : ldb;
    int rt0 = tensor == 0 ? row0 : col0;
    char* dst = sm + tensor * 65536 + buf * 32768 + half * 16384;
#pragma unroll
    for (int r = 0; r < 2; ++r) {
      int o = tid * 16 + r * 8192;
      int row = half * 128 + (o >> 7);
      int cc = (o >> 4) & 7;
      int c = cc ^ (row & 7);  // inverse swizzle on global source (read applies same XOR)
      gld16((const char*)(base + (size_t)(rt0 + row) * ld + ko) + c * 16, dst + o);
    }
  };

  // per-thread swizzled chunk byte offsets (row&7 == lr&7 for all fragments)
  const int c0 = ((0 + lq) ^ (lr & 7)) * 16;
  const int c1 = ((4 + lq) ^ (lr & 7)) * 16;

  f32x4 acc[8][4] = {};
  bf16x8 bf[4][2];

  // prologue: tile0 (all 4 halves) -> buf0; B halves of tile1 -> buf1
  stage(0, 0, 0, 0); stage(0, 1, 0, 0); stage(1, 0, 0, 0); stage(1, 1, 0, 0);
  stage(1, 0, 1, 1); stage(1, 1, 1, 1);
  asm volatile("s_waitcnt vmcnt(4)" ::: "memory");
  __builtin_amdgcn_s_barrier();
  __builtin_amdgcn_sched_barrier(0);

  for (int T = 0; T < NT; ++T) {
    const int buf = T & 1;
    const int a_lds = buf * 32768 + (wm * 128 + lr) * 128;
    const int b_lds = 65536 + buf * 32768 + (wn * 64 + lr) * 128;
#pragma unroll
    for (int p = 0; p < 4; ++p) {
      // stage schedule (region-safe): P0/P1 -> A halves of T+1 (buf^1); P2/P3 -> B halves of T+2 (buf)
      if (p == 0) { if (T + 1 < NT) stage(0, 0, T + 1, buf ^ 1); }
      if (p == 1) { if (T + 1 < NT) stage(0, 1, T + 1, buf ^ 1); }
      if (p == 2) { if (T + 2 < NT) stage(1, 0, T + 2, buf); }
      if (p == 3) { if (T + 2 < NT) stage(1, 1, T + 2, buf); }
      if (p == 0) {
#pragma unroll
        for (int ni = 0; ni < 4; ++ni) {
          bf[ni][0] = *(const bf16x8*)(sm + b_lds + ni * 2048 + c0);
          bf[ni][1] = *(const bf16x8*)(sm + b_lds + ni * 2048 + c1);
        }
      }
      bf16x8 af[2][2];
#pragma unroll
      for (int m2 = 0; m2 < 2; ++m2) {
        af[m2][0] = *(const bf16x8*)(sm + a_lds + (2 * p + m2) * 2048 + c0);
        af[m2][1] = *(const bf16x8*)(sm + a_lds + (2 * p + m2) * 2048 + c1);
      }
      asm volatile("s_waitcnt lgkmcnt(0)" ::: "memory");
      __builtin_amdgcn_sched_barrier(0);
      __builtin_amdgcn_s_setprio(1);
#pragma unroll
      for (int kk = 0; kk < 2; ++kk)
#pragma unroll
        for (int m2 = 0; m2 < 2; ++m2)
#pragma unroll
          for (int ni = 0; ni < 4; ++ni)
            acc[2 * p + m2][ni] = __builtin_amdgcn_mfma_f32_16x16x32_bf16(
                af[m2][kk], bf[ni][kk], acc[2 * p + m2][ni], 0, 0, 0);
      __builtin_amdgcn_s_setprio(0);
      if (p == 3) {
        if (T < NT - 2) asm volatile("s_waitcnt vmcnt(4)" ::: "memory");
        else            asm volatile("s_waitcnt vmcnt(0)" ::: "memory");
      }
      __builtin_amdgcn_s_barrier();
      __builtin_amdgcn_sched_barrier(0);
    }
  }

  // epilogue: C row = (lane>>4)*4 + reg, col = lane&15 (verified layout)
#pragma unroll
  for (int mi = 0; mi < 8; ++mi) {
#pragma unroll
    for (int ni = 0; ni < 4; ++ni) {
      f32x4 v = acc[mi][ni];
#pragma unroll
      for (int jj = 0; jj < 4; ++jj) {
        size_t r = (size_t)(row0 + wm * 128 + mi * 16 + lq * 4 + jj);
        size_t c = (size_t)(col0 + wn * 64 + ni * 16 + lr);
        size_t idx = r * (size_t)ldc + c;
        float val = v[jj] * cscale;
        if constexpr (EPI == 0) {
          bf16* Chp = (bf16*)C0 + bz * sC;
          bf16* Clp = (bf16*)C1 + bz * sC;
          bf16 hh = (bf16)val;
          Chp[idx] = hh;
          Clp[idx] = (bf16)(val - (float)hh);
        } else {
          float* Cp = (float*)C0 + bz * sC;
          Cp[idx] = val;
        }
      }
    }
  }
}

// ---------------- 128^2 GEMM (non-split users: V-proj, PV, O-proj) ----------------
// EPI: 1 = float*cscale (C0); 2 = bf16 (C0); 3 = bf16 transposed V write
template <bool SPLIT, int EPI>
__global__ __launch_bounds__(256, 2) void k_gemm(
    const bf16* __restrict__ Ah, const bf16* __restrict__ Al,
    const bf16* __restrict__ Bh, const bf16* __restrict__ Bl,
    void* __restrict__ C0, void* __restrict__ C1,
    int Kdim, int lda, int ldb, int ldc,
    long long sA, long long sB, long long sC, float cscale) {
  constexpr int NTILES = SPLIT ? 4 : 2;
  __shared__ __align__(16) bf16 smm[NTILES * 128 * 64];
  bf16* smAh = smm;
  bf16* smBh = smm + 128 * 64;
  bf16* smAl = SPLIT ? smm + 2 * 128 * 64 : nullptr;
  bf16* smBl = SPLIT ? smm + 3 * 128 * 64 : nullptr;

  const int tid = threadIdx.x;
  const int lane = tid & 63, wid = tid >> 6;
  const int lr = lane & 15, lq = lane >> 4;
  const int wr = (wid >> 1) * 64, wc = (wid & 1) * 64;
  const long long bz = blockIdx.z;
  const int col0 = blockIdx.x * 128, row0 = blockIdx.y * 128;

  const bf16* pAh = Ah + bz * sA;
  const bf16* pBh = Bh + bz * sB;
  const bf16* pAl = SPLIT ? (Al + bz * sA) : nullptr;
  const bf16* pBl = SPLIT ? (Bl + bz * sB) : nullptr;

  f32x4 acc[4][4] = {};

  for (int kt = 0; kt < Kdim; kt += 64) {
    {
      int o = tid * 16;
#pragma unroll
      for (int r = 0; r < 4; r++, o += 4096) {
        int row = o >> 7;
        int c = (o & 127) ^ ((row & 7) << 4);
        gld16((const char*)(pAh + (size_t)(row0 + row) * lda + kt) + c, (char*)smAh + o);
        gld16((const char*)(pBh + (size_t)(col0 + row) * ldb + kt) + c, (char*)smBh + o);
        if constexpr (SPLIT) {
          gld16((const char*)(pAl + (size_t)(row0 + row) * lda + kt) + c, (char*)smAl + o);
          gld16((const char*)(pBl + (size_t)(col0 + row) * ldb + kt) + c, (char*)smBl + o);
        }
      }
    }
    __syncthreads();
#pragma unroll
    for (int kk = 0; kk < 2; kk++) {
      bf16x8 ah[4], bh[4], al[4], bl[4];
#pragma unroll
      for (int i = 0; i < 4; i++) {
        int ar = wr + i * 16 + lr;
        int ao = ar * 128 + ((kk * 64 + lq * 16) ^ ((ar & 7) << 4));
        ah[i] = *(const bf16x8*)((const char*)smAh + ao);
        int br = wc + i * 16 + lr;
        int bo = br * 128 + ((kk * 64 + lq * 16) ^ ((br & 7) << 4));
        bh[i] = *(const bf16x8*)((const char*)smBh + bo);
        if constexpr (SPLIT) {
          al[i] = *(const bf16x8*)((const char*)smAl + ao);
          bl[i] = *(const bf16x8*)((const char*)smBl + bo);
        }
      }
#pragma unroll
      for (int i = 0; i < 4; i++)
#pragma unroll
        for (int j = 0; j < 4; j++) {
          acc[i][j] = __builtin_amdgcn_mfma_f32_16x16x32_bf16(ah[i], bh[j], acc[i][j], 0, 0, 0);
          if constexpr (SPLIT) {
            acc[i][j] = __builtin_amdgcn_mfma_f32_16x16x32_bf16(ah[i], bl[j], acc[i][j], 0, 0, 0);
            acc[i][j] = __builtin_amdgcn_mfma_f32_16x16x32_bf16(al[i], bh[j], acc[i][j], 0, 0, 0);
          }
        }
    }
    __syncthreads();
  }

#pragma unroll
  for (int i = 0; i < 4; i++) {
#pragma unroll
    for (int j2 = 0; j2 < 4; j2++) {
      f32x4 v = acc[i][j2];
      if constexpr (EPI == 3) {
        int r0 = row0 + wr + i * 16 + lq * 4;
        int c = col0 + wc + j2 * 16 + lr;
        int b = r0 >> 11, n0 = r0 & 2047;
        bf16x4 t;
#pragma unroll
        for (int j = 0; j < 4; j++) t[j] = (bf16)(v[j] * cscale);
        *(bf16x4*)((bf16*)C0 + ((size_t)b * EE + c) * NN + n0) = t;
      } else {
#pragma unroll
        for (int j = 0; j < 4; j++) {
          size_t r = (size_t)(row0 + wr + i * 16 + lq * 4 + j);
          size_t c = (size_t)(col0 + wc + j2 * 16 + lr);
          size_t idx = r * (size_t)ldc + c;
          float val = v[j] * cscale;
          if constexpr (EPI == 1) {
            float* Cp = (float*)C0 + bz * sC;
            Cp[idx] = val;
          } else {
            bf16* Cp = (bf16*)C0 + bz * sC;
            Cp[idx] = (bf16)val;
          }
        }
      }
    }
  }
}

// ---------------- row softmax in-place: S row fp32 -> P bf16 in first half ----------------
__global__ __launch_bounds__(256) void k_softmax(float* __restrict__ S) {
  size_t row = blockIdx.x;
  float* srow = S + row * (size_t)NN;
  int tid = threadIdx.x;
  int wid = tid >> 6, lane = tid & 63;
  const float4* s4 = (const float4*)srow;
  float4 v0 = s4[tid * 2], v1 = s4[tid * 2 + 1];
  float vv[8] = {v0.x, v0.y, v0.z, v0.w, v1.x, v1.y, v1.z, v1.w};
  float m = vv[0];
#pragma unroll
  for (int j = 1; j < 8; j++) m = fmaxf(m, vv[j]);
#pragma unroll
  for (int d = 1; d < 64; d <<= 1) m = fmaxf(m, __shfl_xor(m, d));
  __shared__ float red[8];
  if (lane == 0) red[wid] = m;
  __syncthreads();
  m = fmaxf(fmaxf(red[0], red[1]), fmaxf(red[2], red[3]));
  float e[8];
  float ssum = 0.f;
#pragma unroll
  for (int j = 0; j < 8; j++) { e[j] = __expf(vv[j] - m); ssum += e[j]; }
#pragma unroll
  for (int d = 1; d < 64; d <<= 1) ssum += __shfl_xor(ssum, d);
  if (lane == 0) red[4 + wid] = ssum;
  __syncthreads();
  ssum = red[4] + red[5] + red[6] + red[7];
  float inv = 1.0f / ssum;
  bf16x8 p;
#pragma unroll
  for (int j = 0; j < 8; j++) p[j] = (bf16)(e[j] * inv);
  *(bf16x8*)((bf16*)srow + tid * 8) = p;
}

// ---------------- host ----------------
extern "C" void kernel_launch(void* const* d_in, const int* in_sizes, int n_in,
                              void* d_out, int out_size, void* d_ws, size_t ws_size,
                              hipStream_t stream) {
  const float* x  = (const float*)d_in[0];
  const float* Wq = (const float*)d_in[1];
  const float* Wk = (const float*)d_in[2];
  const float* Wv = (const float*)d_in[3];
  const float* Wo = (const float*)d_in[4];
  float* out = (float*)d_out;
  char* ws = (char*)d_ws;

  const size_t szXE = (size_t)MM * EE * 2;      // 25.17 MB
  const size_t szWb = (size_t)EE * EE * 2;      // 1.18 MB
  const size_t szQKh = (size_t)MM * E2 * 2;     // 50.33 MB
  const size_t szS1 = (size_t)NN * NN * 4;      // 16.78 MB

  bf16* xhi = (bf16*)(ws);
  bf16* xlo = (bf16*)(ws + szXE);
  char* wb  = ws + 2 * szXE;
  bf16* wqkh = (bf16*)(wb);
  bf16* wqkl = (bf16*)(wb + 2 * szWb);
  bf16* wvb  = (bf16*)(wb + 4 * szWb);
  bf16* wob  = (bf16*)(wb + 5 * szWb);
  char* qkb = wb + 6 * szWb;
  bf16* QKh = (bf16*)(qkb);
  bf16* QKl = (bf16*)(qkb + szQKh);
  bf16* Vt  = (bf16*)(qkb + 2 * szQKh);
  char* Sb  = qkb + 2 * szQKh + szXE;
  float* S  = (float*)Sb;
  bf16* Ao  = (bf16*)ws;  // overlay x-split (dead after projections)

  size_t oS = (size_t)(Sb - ws);
  size_t avail = ws_size > oS ? ws_size - oS : 0;
  int G = 8;
  while (G > 1 && (size_t)G * szS1 > avail) G >>= 1;

  k_splitx<<<2048, 256, 0, stream>>>((const float4*)x, (bf16x4*)xhi, (bf16x4*)xlo, MM * EE / 4);
  k_wprep<<<dim3(144, 4), 256, 0, stream>>>((const float4*)Wq, (const float4*)Wk,
                                            (const float4*)Wv, (const float4*)Wo,
                                            (bf16x4*)wqkh, (bf16x4*)wqkl, (bf16x4*)wvb, (bf16x4*)wob);

  // merged Q|K projection: panels A=[xh|xh|xl], B=[Wh|Wl|Wh]; grid (1536/256, 16384/256)
  k_gemm3p8<0><<<dim3(E2 / 256, MM / 256, 1), 512, 0, stream>>>(
      xhi, xhi, xlo, wqkh, wqkl, wqkh, QKh, QKl, EE, EE, E2, 0, 0, 0, 1.0f);
  // V projection, written transposed
  k_gemm<false, 3><<<dim3(EE / 128, MM / 128, 1), 256, 0, stream>>>(
      xhi, nullptr, wvb, nullptr, Vt, nullptr, EE, EE, EE, 0, 0, 0, 0, 1.0f);

  const long long sQK = (long long)NN * E2;
  for (int g = 0; g < BB; g += G) {
    const bf16* Qh = QKh + (size_t)g * NN * E2;
    const bf16* Ql = QKl + (size_t)g * NN * E2;
    // S = 8 * Q @ K^T: panels A=[Qh|Qh|Ql], B=[Kh|Kl|Kh]; grid (2048/256, 2048/256, G)
    k_gemm3p8<1><<<dim3(NN / 256, NN / 256, G), 512, 0, stream>>>(
        Qh, Qh, Ql, Qh + EE, Ql + EE, Qh + EE, S, nullptr, E2, E2, NN,
        sQK, sQK, (long long)NN * NN, 8.0f);
    k_softmax<<<G * NN, 256, 0, stream>>>(S);
    k_gemm<false, 2><<<dim3(EE / 128, NN / 128, G), 256, 0, stream>>>(
        (const bf16*)S, nullptr, Vt + (size_t)g * EE * NN, nullptr,
        Ao + (size_t)g * NN * EE, nullptr, NN, 2 * NN, NN, EE,
        2LL * NN * NN, (long long)EE * NN, (long long)NN * EE, 1.0f);
  }

  k_gemm<false, 1><<<dim3(EE / 128, MM / 128, 1), 256, 0, stream>>>(
      Ao, nullptr, wob, nullptr, out, nullptr, EE, EE, EE, EE, 0, 0, 0, 1.0f);
}